// Round 1
// baseline (657.723 us; speedup 1.0000x reference)
//
#include <hip/hip_runtime.h>
#include <cstdint>
#include <cstddef>

typedef _Float16 h16;
typedef _Float16 h16x8 __attribute__((ext_vector_type(8)));
typedef float f32x4 __attribute__((ext_vector_type(4)));

#define LOG2E 1.44269504088896f

static __device__ __forceinline__ f32x4 mfma_f16(h16x8 a, h16x8 b, f32x4 c) {
  return __builtin_amdgcn_mfma_f32_16x16x32_f16(a, b, c, 0, 0, 0);
}

static __device__ __forceinline__ void gload_lds16(const void* g, void* s) {
  __builtin_amdgcn_global_load_lds(
      (__attribute__((address_space(1))) void*)(uintptr_t)g,
      (__attribute__((address_space(3))) void*)s, 16, 0, 0);
}

// ---------------- fp32 -> fp16 convert (vectorized) ----------------
__global__ __launch_bounds__(256) void k_cvt(const float* __restrict__ in,
                                             h16* __restrict__ out, int n) {
  int i = (blockIdx.x * 256 + threadIdx.x) * 8;
  if (i >= n) return;
  float4 a = *(const float4*)(in + i);
  float4 b = *(const float4*)(in + i + 4);
  h16x8 o;
  o[0] = (h16)a.x; o[1] = (h16)a.y; o[2] = (h16)a.z; o[3] = (h16)a.w;
  o[4] = (h16)b.x; o[5] = (h16)b.y; o[6] = (h16)b.z; o[7] = (h16)b.w;
  *(h16x8*)(out + i) = o;
}

// ---------------- fp32 [R][C] -> fp16 [C][R] transpose-convert ----------------
__global__ __launch_bounds__(256) void k_tr_cvt(const float* __restrict__ in,
                                                h16* __restrict__ out, int R, int C) {
  __shared__ float tile[32][33];
  int c0 = blockIdx.x * 32, r0 = blockIdx.y * 32;
  int tx = threadIdx.x & 31, ty = threadIdx.x >> 5;
#pragma unroll
  for (int i = 0; i < 4; i++) {
    int r = ty + i * 8;
    tile[r][tx] = in[(size_t)(r0 + r) * C + c0 + tx];
  }
  __syncthreads();
#pragma unroll
  for (int i = 0; i < 4; i++) {
    int c = ty + i * 8;
    out[(size_t)(c0 + c) * R + r0 + tx] = (h16)tile[tx][c];
  }
}

// ---------------- 128x128 tile GEMM mainloop: C = A[M][K] * BT[N][K]^T ----------------
static __device__ __forceinline__ void gemm_main(const h16* __restrict__ A,
                                                 const h16* __restrict__ BT,
                                                 int K, int m0, int n0,
                                                 h16* sA, h16* sB, f32x4 acc[4][4]) {
  const int t = threadIdx.x;
  const int l = t & 63, w = t >> 6;
  const int lm = l & 15, lh = l >> 4;
  const int wm = (w >> 1) * 64, wn = (w & 1) * 64;

  const h16* gA0 = A + (size_t)(m0 + (t >> 2)) * K + (t & 3) * 8;
  const h16* gB0 = BT + (size_t)(n0 + (t >> 2)) * K + (t & 3) * 8;
  h16* sAw = sA + w * 512;  // wave-uniform LDS staging base (elements)
  h16* sBw = sB + w * 512;

  for (int k0 = 0; k0 < K; k0 += 32) {
    gload_lds16(gA0 + k0, sAw);
    gload_lds16(gA0 + (size_t)64 * K + k0, sAw + 2048);
    gload_lds16(gB0 + k0, sBw);
    gload_lds16(gB0 + (size_t)64 * K + k0, sBw + 2048);
    __syncthreads();
    h16x8 af[4], bfv[4];
#pragma unroll
    for (int mi = 0; mi < 4; mi++)
      af[mi] = *(const h16x8*)(sA + (wm + mi * 16 + lm) * 32 + lh * 8);
#pragma unroll
    for (int ni = 0; ni < 4; ni++)
      bfv[ni] = *(const h16x8*)(sB + (wn + ni * 16 + lm) * 32 + lh * 8);
#pragma unroll
    for (int mi = 0; mi < 4; mi++)
#pragma unroll
      for (int ni = 0; ni < 4; ni++)
        acc[mi][ni] = mfma_f16(af[mi], bfv[ni], acc[mi][ni]);
    __syncthreads();
  }
}

// ---------------- GEMM1: qkv = x @ W_attn + b; scatter q,k:[B,Nh,S,Ne], v^T:[B,Nh,Ne,S] ----------------
__global__ __launch_bounds__(256) void k_gemm_qkv(const h16* __restrict__ xb,
                                                  const h16* __restrict__ WTa,
                                                  const float* __restrict__ b_attn,
                                                  h16* __restrict__ qb, h16* __restrict__ kbuf,
                                                  h16* __restrict__ vT) {
  __shared__ __align__(16) h16 sA[128 * 32];
  __shared__ __align__(16) h16 sB[128 * 32];
  f32x4 acc[4][4];
#pragma unroll
  for (int i = 0; i < 4; i++)
#pragma unroll
    for (int j = 0; j < 4; j++) acc[i][j] = (f32x4){0.f, 0.f, 0.f, 0.f};
  const int n0 = blockIdx.x * 128, m0 = blockIdx.y * 128;
  gemm_main(xb, WTa, 1024, m0, n0, sA, sB, acc);

  const int t = threadIdx.x, l = t & 63, w = t >> 6;
  const int lm = l & 15, lh = l >> 4;
  const int wm = (w >> 1) * 64, wn = (w & 1) * 64;
#pragma unroll
  for (int mi = 0; mi < 4; mi++) {
#pragma unroll
    for (int ni = 0; ni < 4; ni++) {
      const int n = n0 + wn + ni * 16 + lm;
      const float bias = b_attn[n];
      const int which = n >> 10, c = n & 1023, h = c >> 6, e = c & 63;
#pragma unroll
      for (int r = 0; r < 4; r++) {
        const int m = m0 + wm + mi * 16 + lh * 4 + r;
        const int b = m >> 11, s = m & 2047;
        const h16 o = (h16)(acc[mi][ni][r] + bias);
        const size_t bh = (size_t)(b * 16 + h);
        if (which == 0)      qb[(bh * 2048 + s) * 64 + e] = o;
        else if (which == 1) kbuf[(bh * 2048 + s) * 64 + e] = o;
        else                 vT[(bh * 64 + e) * 2048 + s] = o;
      }
    }
  }
}

// ---------------- GEMM2: out = y @ W_proj + b (fp32 out) ----------------
__global__ __launch_bounds__(256) void k_gemm_proj(const h16* __restrict__ yb,
                                                   const h16* __restrict__ WTp,
                                                   const float* __restrict__ b_proj,
                                                   float* __restrict__ out) {
  __shared__ __align__(16) h16 sA[128 * 32];
  __shared__ __align__(16) h16 sB[128 * 32];
  f32x4 acc[4][4];
#pragma unroll
  for (int i = 0; i < 4; i++)
#pragma unroll
    for (int j = 0; j < 4; j++) acc[i][j] = (f32x4){0.f, 0.f, 0.f, 0.f};
  const int n0 = blockIdx.x * 128, m0 = blockIdx.y * 128;
  gemm_main(yb, WTp, 1024, m0, n0, sA, sB, acc);

  const int t = threadIdx.x, l = t & 63, w = t >> 6;
  const int lm = l & 15, lh = l >> 4;
  const int wm = (w >> 1) * 64, wn = (w & 1) * 64;
#pragma unroll
  for (int mi = 0; mi < 4; mi++) {
#pragma unroll
    for (int ni = 0; ni < 4; ni++) {
      const int n = n0 + wn + ni * 16 + lm;
      const float bias = b_proj[n];
#pragma unroll
      for (int r = 0; r < 4; r++) {
        const int m = m0 + wm + mi * 16 + lh * 4 + r;
        out[(size_t)m * 1024 + n] = acc[mi][ni][r] + bias;
      }
    }
  }
}

// ---------------- causal flash attention ----------------
// grid: 64 (b,h) * 32 q-tiles; block 256 = 4 waves, 16 q-rows per wave, KV step 32
__global__ __launch_bounds__(256) void k_attn(const h16* __restrict__ qb,
                                              const h16* __restrict__ kbuf,
                                              const h16* __restrict__ vT,
                                              h16* __restrict__ yb) {
  __shared__ __align__(16) h16 Psm[4][2][16][48];  // per-wave, double-buffered, padded
  const int bid = blockIdx.x;
  const int qt = bid & 31;
  const int bh = bid >> 5;
  const int b = bh >> 4, h = bh & 15;
  const int t = threadIdx.x, l = t & 63, w = t >> 6;
  const int lm = l & 15, lh = l >> 4;
  const int q0 = qt * 64 + w * 16;
  const h16* Q = qb + (size_t)bh * 2048 * 64;
  const h16* Kp = kbuf + (size_t)bh * 2048 * 64;
  const h16* Vp = vT + (size_t)bh * 64 * 2048;

  h16x8 qf[2];
#pragma unroll
  for (int db = 0; db < 2; db++)
    qf[db] = *(const h16x8*)(Q + (size_t)(q0 + lm) * 64 + db * 32 + lh * 8);

  f32x4 yacc[4];
  float mrow[4], lrow[4];
#pragma unroll
  for (int i = 0; i < 4; i++) {
    yacc[i] = (f32x4){0.f, 0.f, 0.f, 0.f};
    mrow[i] = -1e30f;
    lrow[i] = 0.f;
  }

  const int kend = q0 + 16;  // causal: cols < q0+16 needed for this wave's 16 rows
  for (int kb0 = 0; kb0 < kend; kb0 += 32) {
    const int pb = (kb0 >> 5) & 1;
    f32x4 sv[2];
#pragma unroll
    for (int kt = 0; kt < 2; kt++) {
      f32x4 s = (f32x4){0.f, 0.f, 0.f, 0.f};
#pragma unroll
      for (int db = 0; db < 2; db++) {
        h16x8 kf = *(const h16x8*)(Kp + (size_t)(kb0 + kt * 16 + lm) * 64 + db * 32 + lh * 8);
        s = mfma_f16(qf[db], kf, s);
      }
      sv[kt] = s;
    }
    // online softmax over this 16x32 tile (per q-row: 16-lane group reduce)
#pragma unroll
    for (int r = 0; r < 4; r++) {
      const int qrow = q0 + lh * 4 + r;
      float v0 = sv[0][r] * 0.125f;
      float v1 = sv[1][r] * 0.125f;
      if (kb0 + lm > qrow) v0 = -1e30f;
      if (kb0 + 16 + lm > qrow) v1 = -1e30f;
      float rm = fmaxf(v0, v1);
#pragma unroll
      for (int off = 1; off < 16; off <<= 1) rm = fmaxf(rm, __shfl_xor(rm, off));
      const float nm = fmaxf(mrow[r], rm);
      const float alpha = exp2f((mrow[r] - nm) * LOG2E);
      const float p0 = exp2f((v0 - nm) * LOG2E);
      const float p1 = exp2f((v1 - nm) * LOG2E);
      float ps = p0 + p1;
#pragma unroll
      for (int off = 1; off < 16; off <<= 1) ps += __shfl_xor(ps, off);
      lrow[r] = lrow[r] * alpha + ps;
      mrow[r] = nm;
#pragma unroll
      for (int dn = 0; dn < 4; dn++) yacc[dn][r] *= alpha;
      Psm[w][pb][lh * 4 + r][lm] = (h16)p0;
      Psm[w][pb][lh * 4 + r][16 + lm] = (h16)p1;
    }
    // wave-local LDS write -> read ordering (no __syncthreads: per-wave buffers)
    asm volatile("s_waitcnt lgkmcnt(0)" ::: "memory");
    __builtin_amdgcn_sched_barrier(0);
    h16x8 pf = *(const h16x8*)(&Psm[w][pb][lm][lh * 8]);
#pragma unroll
    for (int dn = 0; dn < 4; dn++) {
      h16x8 vf = *(const h16x8*)(Vp + (size_t)(dn * 16 + lm) * 2048 + kb0 + lh * 8);
      yacc[dn] = mfma_f16(pf, vf, yacc[dn]);
    }
  }
#pragma unroll
  for (int r = 0; r < 4; r++) {
    const int qrow = q0 + lh * 4 + r;
    const float inv = 1.f / lrow[r];
#pragma unroll
    for (int dn = 0; dn < 4; dn++)
      yb[((size_t)b * 2048 + qrow) * 1024 + h * 64 + dn * 16 + lm] =
          (h16)(yacc[dn][r] * inv);
  }
}

extern "C" void kernel_launch(void* const* d_in, const int* in_sizes, int n_in,
                              void* d_out, int out_size, void* d_ws, size_t ws_size,
                              hipStream_t stream) {
  const float* x      = (const float*)d_in[0];
  const float* W_attn = (const float*)d_in[1];
  const float* b_attn = (const float*)d_in[2];
  const float* W_proj = (const float*)d_in[3];
  const float* b_proj = (const float*)d_in[4];
  float* out = (float*)d_out;

  char* ws = (char*)d_ws;
  h16* xb   = (h16*)(ws);                 // 16 MB  [8192][1024] fp16 (reused as yb)
  h16* WTa  = (h16*)(ws + 16777216);      // 6 MB   [3072][1024]
  h16* WTp  = (h16*)(ws + 23068672);      // 2 MB   [1024][1024]
  h16* qb   = (h16*)(ws + 25165824);      // 16 MB  [B,Nh,S,Ne]
  h16* kbuf = (h16*)(ws + 41943040);      // 16 MB  [B,Nh,S,Ne]
  h16* vT   = (h16*)(ws + 58720256);      // 16 MB  [B,Nh,Ne,S]
  h16* yb   = xb;                         // reuse x buffer for attention output

  k_cvt<<<dim3(8192 * 1024 / 2048), 256, 0, stream>>>(x, xb, 8192 * 1024);
  k_tr_cvt<<<dim3(3072 / 32, 1024 / 32), 256, 0, stream>>>(W_attn, WTa, 1024, 3072);
  k_tr_cvt<<<dim3(1024 / 32, 1024 / 32), 256, 0, stream>>>(W_proj, WTp, 1024, 1024);
  k_gemm_qkv<<<dim3(3072 / 128, 8192 / 128), 256, 0, stream>>>(xb, WTa, b_attn, qb, kbuf, vT);
  k_attn<<<dim3(64 * 32), 256, 0, stream>>>(qb, kbuf, vT, yb);
  k_gemm_proj<<<dim3(1024 / 128, 8192 / 128), 256, 0, stream>>>(yb, WTp, b_proj, out);
}

// Round 2
// 350.112 us; speedup vs baseline: 1.8786x; 1.8786x over previous
//
#include <hip/hip_runtime.h>
#include <cstdint>
#include <cstddef>

typedef _Float16 h16;
typedef _Float16 h16x8 __attribute__((ext_vector_type(8)));
typedef float f32x4 __attribute__((ext_vector_type(4)));

#define LOG2E 1.44269504088896f
#define QSCALE (0.125f * LOG2E)
#define THR 11.0f

static __device__ __forceinline__ f32x4 mfma_f16(h16x8 a, h16x8 b, f32x4 c) {
  return __builtin_amdgcn_mfma_f32_16x16x32_f16(a, b, c, 0, 0, 0);
}

static __device__ __forceinline__ void gload_lds16(const void* g, void* s) {
  __builtin_amdgcn_global_load_lds(
      (__attribute__((address_space(1))) void*)(uintptr_t)g,
      (__attribute__((address_space(3))) void*)s, 16, 0, 0);
}

// ---------------- fp32 -> fp16 convert (vectorized) ----------------
__global__ __launch_bounds__(256) void k_cvt(const float* __restrict__ in,
                                             h16* __restrict__ out, int n) {
  int i = (blockIdx.x * 256 + threadIdx.x) * 8;
  if (i >= n) return;
  float4 a = *(const float4*)(in + i);
  float4 b = *(const float4*)(in + i + 4);
  h16x8 o;
  o[0] = (h16)a.x; o[1] = (h16)a.y; o[2] = (h16)a.z; o[3] = (h16)a.w;
  o[4] = (h16)b.x; o[5] = (h16)b.y; o[6] = (h16)b.z; o[7] = (h16)b.w;
  *(h16x8*)(out + i) = o;
}

// ---------------- fp32 [R][C] -> fp16 [C][R] transpose-convert ----------------
__global__ __launch_bounds__(256) void k_tr_cvt(const float* __restrict__ in,
                                                h16* __restrict__ out, int R, int C) {
  __shared__ float tile[32][33];
  int c0 = blockIdx.x * 32, r0 = blockIdx.y * 32;
  int tx = threadIdx.x & 31, ty = threadIdx.x >> 5;
#pragma unroll
  for (int i = 0; i < 4; i++) {
    int r = ty + i * 8;
    tile[r][tx] = in[(size_t)(r0 + r) * C + c0 + tx];
  }
  __syncthreads();
#pragma unroll
  for (int i = 0; i < 4; i++) {
    int c = ty + i * 8;
    out[(size_t)(c0 + c) * R + r0 + tx] = (h16)tile[tx][c];
  }
}

// ---------------- 128x128 tile GEMM mainloop: C = A[M][K] * BT[N][K]^T ----------------
static __device__ __forceinline__ void gemm_main(const h16* __restrict__ A,
                                                 const h16* __restrict__ BT,
                                                 int K, int m0, int n0,
                                                 h16* sA, h16* sB, f32x4 acc[4][4]) {
  const int t = threadIdx.x;
  const int l = t & 63, w = t >> 6;
  const int lm = l & 15, lh = l >> 4;
  const int wm = (w >> 1) * 64, wn = (w & 1) * 64;

  const h16* gA0 = A + (size_t)(m0 + (t >> 2)) * K + (t & 3) * 8;
  const h16* gB0 = BT + (size_t)(n0 + (t >> 2)) * K + (t & 3) * 8;
  h16* sAw = sA + w * 512;
  h16* sBw = sB + w * 512;

  for (int k0 = 0; k0 < K; k0 += 32) {
    gload_lds16(gA0 + k0, sAw);
    gload_lds16(gA0 + (size_t)64 * K + k0, sAw + 2048);
    gload_lds16(gB0 + k0, sBw);
    gload_lds16(gB0 + (size_t)64 * K + k0, sBw + 2048);
    __syncthreads();
    h16x8 af[4], bfv[4];
#pragma unroll
    for (int mi = 0; mi < 4; mi++)
      af[mi] = *(const h16x8*)(sA + (wm + mi * 16 + lm) * 32 + lh * 8);
#pragma unroll
    for (int ni = 0; ni < 4; ni++)
      bfv[ni] = *(const h16x8*)(sB + (wn + ni * 16 + lm) * 32 + lh * 8);
#pragma unroll
    for (int mi = 0; mi < 4; mi++)
#pragma unroll
      for (int ni = 0; ni < 4; ni++)
        acc[mi][ni] = mfma_f16(af[mi], bfv[ni], acc[mi][ni]);
    __syncthreads();
  }
}

// ---------------- GEMM1: qkv = x @ W_attn + b; scatter q,k:[B,Nh,S,Ne], v^T:[B,Nh,Ne,S] ----------------
__global__ __launch_bounds__(256) void k_gemm_qkv(const h16* __restrict__ xb,
                                                  const h16* __restrict__ WTa,
                                                  const float* __restrict__ b_attn,
                                                  h16* __restrict__ qb, h16* __restrict__ kbuf,
                                                  h16* __restrict__ vT) {
  __shared__ __align__(16) h16 sA[128 * 32];
  __shared__ __align__(16) h16 sB[128 * 32];
  f32x4 acc[4][4];
#pragma unroll
  for (int i = 0; i < 4; i++)
#pragma unroll
    for (int j = 0; j < 4; j++) acc[i][j] = (f32x4){0.f, 0.f, 0.f, 0.f};
  const int n0 = blockIdx.x * 128, m0 = blockIdx.y * 128;
  gemm_main(xb, WTa, 1024, m0, n0, sA, sB, acc);

  const int t = threadIdx.x, l = t & 63, w = t >> 6;
  const int lm = l & 15, lh = l >> 4;
  const int wm = (w >> 1) * 64, wn = (w & 1) * 64;
#pragma unroll
  for (int mi = 0; mi < 4; mi++) {
#pragma unroll
    for (int ni = 0; ni < 4; ni++) {
      const int n = n0 + wn + ni * 16 + lm;
      const float bias = b_attn[n];
      const int which = n >> 10, c = n & 1023, h = c >> 6, e = c & 63;
#pragma unroll
      for (int r = 0; r < 4; r++) {
        const int m = m0 + wm + mi * 16 + lh * 4 + r;
        const int b = m >> 11, s = m & 2047;
        const h16 o = (h16)(acc[mi][ni][r] + bias);
        const size_t bh = (size_t)(b * 16 + h);
        if (which == 0)      qb[(bh * 2048 + s) * 64 + e] = o;
        else if (which == 1) kbuf[(bh * 2048 + s) * 64 + e] = o;
        else                 vT[(bh * 64 + e) * 2048 + s] = o;
      }
    }
  }
}

// ---------------- GEMM2: out = y @ W_proj + b (fp32 out) ----------------
__global__ __launch_bounds__(256) void k_gemm_proj(const h16* __restrict__ yb,
                                                   const h16* __restrict__ WTp,
                                                   const float* __restrict__ b_proj,
                                                   float* __restrict__ out) {
  __shared__ __align__(16) h16 sA[128 * 32];
  __shared__ __align__(16) h16 sB[128 * 32];
  f32x4 acc[4][4];
#pragma unroll
  for (int i = 0; i < 4; i++)
#pragma unroll
    for (int j = 0; j < 4; j++) acc[i][j] = (f32x4){0.f, 0.f, 0.f, 0.f};
  const int n0 = blockIdx.x * 128, m0 = blockIdx.y * 128;
  gemm_main(yb, WTp, 1024, m0, n0, sA, sB, acc);

  const int t = threadIdx.x, l = t & 63, w = t >> 6;
  const int lm = l & 15, lh = l >> 4;
  const int wm = (w >> 1) * 64, wn = (w & 1) * 64;
#pragma unroll
  for (int mi = 0; mi < 4; mi++) {
#pragma unroll
    for (int ni = 0; ni < 4; ni++) {
      const int n = n0 + wn + ni * 16 + lm;
      const float bias = b_proj[n];
#pragma unroll
      for (int r = 0; r < 4; r++) {
        const int m = m0 + wm + mi * 16 + lh * 4 + r;
        out[(size_t)m * 1024 + n] = acc[mi][ni][r] + bias;
      }
    }
  }
}

// ---------------- causal flash attention, v2 ----------------
// 4 waves/block, 32 q-rows/wave (128/block), KVBLK=64, defer-max (T13),
// lane-partial row-sums, conflict-free P LDS [4][32][20] with ct-stride 648.
#define CTS 648
#define PROW 20
#define PSM_WAVE (4 * CTS)

template <bool MASK>
static __device__ __forceinline__ void attn_tile(
    int kb0, int q0, int lm, int lh,
    const h16* __restrict__ Kp, const h16* __restrict__ Vp, h16* psm,
    const h16x8 (&qf)[2][2], f32x4 (&yacc)[2][4],
    float (&m2)[2][4], float (&lw)[2][4]) {
  // K fragments (B-operand): row = k-col (ct*16+lm), k-elems = d (lh*8..)
  h16x8 kf[4][2];
#pragma unroll
  for (int ct = 0; ct < 4; ct++)
#pragma unroll
    for (int dc = 0; dc < 2; dc++)
      kf[ct][dc] = *(const h16x8*)(Kp + (size_t)(kb0 + ct * 16 + lm) * 64 + dc * 32 + lh * 8);

  // QK^T: sv[rt][ct] = (Q*scale*log2e) . K   (exp2 domain directly)
  f32x4 sv[2][4];
#pragma unroll
  for (int rt = 0; rt < 2; rt++)
#pragma unroll
    for (int ct = 0; ct < 4; ct++) {
      f32x4 s = mfma_f16(qf[rt][0], kf[ct][0], (f32x4){0.f, 0.f, 0.f, 0.f});
      sv[rt][ct] = mfma_f16(qf[rt][1], kf[ct][1], s);
    }

  // V fragments issued early: latency hides under softmax VALU
  h16x8 vf[4][2];
#pragma unroll
  for (int dt = 0; dt < 4; dt++)
#pragma unroll
    for (int kc = 0; kc < 2; kc++)
      vf[dt][kc] = *(const h16x8*)(Vp + (size_t)(dt * 16 + lm) * 2048 + kb0 + kc * 32 + lh * 8);

  if (MASK) {
#pragma unroll
    for (int rt = 0; rt < 2; rt++)
#pragma unroll
      for (int ct = 0; ct < 4; ct++) {
        const int col = kb0 + ct * 16 + lm;
#pragma unroll
        for (int r = 0; r < 4; r++) {
          const int qrow = q0 + rt * 16 + lh * 4 + r;
          if (col > qrow) sv[rt][ct][r] = -1e30f;
        }
      }
  }

  // T13 defer-max: lane-local row max + single ballot; shfl-reduce only when needed
  float rm[2][4];
  bool ok = true;
#pragma unroll
  for (int rt = 0; rt < 2; rt++)
#pragma unroll
    for (int r = 0; r < 4; r++) {
      float a = fmaxf(sv[rt][0][r], sv[rt][1][r]);
      float c = fmaxf(sv[rt][2][r], sv[rt][3][r]);
      rm[rt][r] = fmaxf(a, c);
      ok = ok && (rm[rt][r] <= m2[rt][r] + THR);
    }
  if (!__all((int)ok)) {
#pragma unroll
    for (int rt = 0; rt < 2; rt++)
#pragma unroll
      for (int r = 0; r < 4; r++) {
        float v = rm[rt][r];
#pragma unroll
        for (int off = 1; off < 16; off <<= 1) v = fmaxf(v, __shfl_xor(v, off));
        const float nm = fmaxf(m2[rt][r], v);
        const float alpha = __builtin_amdgcn_exp2f(m2[rt][r] - nm);
        m2[rt][r] = nm;
        lw[rt][r] *= alpha;
#pragma unroll
        for (int dt = 0; dt < 4; dt++) yacc[rt][dt][r] *= alpha;
      }
  }

  // p = exp2(s2 - m2); lane-partial row sums; store P (fp16) to LDS
#pragma unroll
  for (int rt = 0; rt < 2; rt++)
#pragma unroll
    for (int r = 0; r < 4; r++) {
      const float m = m2[rt][r];
      const float p0 = __builtin_amdgcn_exp2f(sv[rt][0][r] - m);
      const float p1 = __builtin_amdgcn_exp2f(sv[rt][1][r] - m);
      const float p2 = __builtin_amdgcn_exp2f(sv[rt][2][r] - m);
      const float p3 = __builtin_amdgcn_exp2f(sv[rt][3][r] - m);
      lw[rt][r] += (p0 + p1) + (p2 + p3);
      const int row = rt * 16 + lh * 4 + r;
      psm[0 * CTS + row * PROW + lm] = (h16)p0;
      psm[1 * CTS + row * PROW + lm] = (h16)p1;
      psm[2 * CTS + row * PROW + lm] = (h16)p2;
      psm[3 * CTS + row * PROW + lm] = (h16)p3;
    }
  // wave-local write->read ordering (per-wave LDS region; DS pipe is in-order,
  // the fence + sched_barrier stops compiler reordering - rule #18)
  asm volatile("s_waitcnt lgkmcnt(0)" ::: "memory");
  __builtin_amdgcn_sched_barrier(0);

  // P as A-fragment: row=q(lm), k = kc*32 + lh*8 + i  -> ct = kc*2+(lh>>1)
#pragma unroll
  for (int rt = 0; rt < 2; rt++) {
    const h16x8 pf0 = *(const h16x8*)(psm + (lh >> 1) * CTS + (rt * 16 + lm) * PROW + (lh & 1) * 8);
    const h16x8 pf1 = *(const h16x8*)(psm + (2 + (lh >> 1)) * CTS + (rt * 16 + lm) * PROW + (lh & 1) * 8);
#pragma unroll
    for (int dt = 0; dt < 4; dt++) {
      f32x4 y = mfma_f16(pf0, vf[dt][0], yacc[rt][dt]);
      yacc[rt][dt] = mfma_f16(pf1, vf[dt][1], y);
    }
  }
}

__global__ __launch_bounds__(256, 3) void k_attn(const h16* __restrict__ qb,
                                                 const h16* __restrict__ kbuf,
                                                 const h16* __restrict__ vT,
                                                 h16* __restrict__ yb) {
  __shared__ __align__(16) h16 Psm[4 * PSM_WAVE];
  const int bid = blockIdx.x;
  const int bh = bid & 63;          // same-head blocks 64 apart -> same XCD
  const int qt = 15 - (bid >> 6);   // long blocks dispatch first
  const int b = bh >> 4, h = bh & 15;
  const int t = threadIdx.x, l = t & 63, w = t >> 6;
  const int lm = l & 15, lh = l >> 4;
  const int q0 = qt * 128 + w * 32;
  const h16* Q = qb + (size_t)bh * 2048 * 64;
  const h16* Kp = kbuf + (size_t)bh * 2048 * 64;
  const h16* Vp = vT + (size_t)bh * 64 * 2048;
  h16* psm = Psm + w * PSM_WAVE;

  // Q fragments, prescaled by 0.125*log2(e) so QK^T lands in exp2 domain
  h16x8 qf[2][2];
#pragma unroll
  for (int rt = 0; rt < 2; rt++)
#pragma unroll
    for (int dc = 0; dc < 2; dc++) {
      h16x8 qv = *(const h16x8*)(Q + (size_t)(q0 + rt * 16 + lm) * 64 + dc * 32 + lh * 8);
      h16x8 o;
#pragma unroll
      for (int i = 0; i < 8; i++) o[i] = (h16)((float)qv[i] * QSCALE);
      qf[rt][dc] = o;
    }

  f32x4 yacc[2][4];
  float m2[2][4], lw[2][4];
#pragma unroll
  for (int rt = 0; rt < 2; rt++)
#pragma unroll
    for (int i = 0; i < 4; i++) {
      yacc[rt][i] = (f32x4){0.f, 0.f, 0.f, 0.f};
      m2[rt][i] = -1e30f;
      lw[rt][i] = 0.f;
    }

  const int nfull = (q0 + 1) >> 6;  // tiles fully below the diagonal for all 32 rows
  for (int kb0 = 0; kb0 < nfull * 64; kb0 += 64)
    attn_tile<false>(kb0, q0, lm, lh, Kp, Vp, psm, qf, yacc, m2, lw);
  attn_tile<true>(nfull * 64, q0, lm, lh, Kp, Vp, psm, qf, yacc, m2, lw);

  // epilogue: one cross-lane sum reduce per row, normalize, store
#pragma unroll
  for (int rt = 0; rt < 2; rt++)
#pragma unroll
    for (int r = 0; r < 4; r++) {
      float s = lw[rt][r];
#pragma unroll
      for (int off = 1; off < 16; off <<= 1) s += __shfl_xor(s, off);
      const float inv = 1.0f / s;
      const int qrow = q0 + rt * 16 + lh * 4 + r;
#pragma unroll
      for (int dt = 0; dt < 4; dt++)
        yb[((size_t)b * 2048 + qrow) * 1024 + h * 64 + dt * 16 + lm] =
            (h16)(yacc[rt][dt][r] * inv);
    }
}

extern "C" void kernel_launch(void* const* d_in, const int* in_sizes, int n_in,
                              void* d_out, int out_size, void* d_ws, size_t ws_size,
                              hipStream_t stream) {
  const float* x      = (const float*)d_in[0];
  const float* W_attn = (const float*)d_in[1];
  const float* b_attn = (const float*)d_in[2];
  const float* W_proj = (const float*)d_in[3];
  const float* b_proj = (const float*)d_in[4];
  float* out = (float*)d_out;

  char* ws = (char*)d_ws;
  h16* xb   = (h16*)(ws);                 // 16 MB  [8192][1024] fp16 (reused as yb)
  h16* WTa  = (h16*)(ws + 16777216);      // 6 MB   [3072][1024]
  h16* WTp  = (h16*)(ws + 23068672);      // 2 MB   [1024][1024]
  h16* qb   = (h16*)(ws + 25165824);      // 16 MB  [B,Nh,S,Ne]
  h16* kbuf = (h16*)(ws + 41943040);      // 16 MB  [B,Nh,S,Ne]
  h16* vT   = (h16*)(ws + 58720256);      // 16 MB  [B,Nh,Ne,S]
  h16* yb   = xb;                         // reuse x buffer for attention output

  k_cvt<<<dim3(8192 * 1024 / 2048), 256, 0, stream>>>(x, xb, 8192 * 1024);
  k_tr_cvt<<<dim3(3072 / 32, 1024 / 32), 256, 0, stream>>>(W_attn, WTa, 1024, 3072);
  k_tr_cvt<<<dim3(1024 / 32, 1024 / 32), 256, 0, stream>>>(W_proj, WTp, 1024, 1024);
  k_gemm_qkv<<<dim3(3072 / 128, 8192 / 128), 256, 0, stream>>>(xb, WTa, b_attn, qb, kbuf, vT);
  k_attn<<<dim3(64 * 16), 256, 0, stream>>>(qb, kbuf, vT, yb);
  k_gemm_proj<<<dim3(1024 / 128, 8192 / 128), 256, 0, stream>>>(yb, WTp, b_proj, out);
}

// Round 5
// 299.471 us; speedup vs baseline: 2.1963x; 1.1691x over previous
//
#include <hip/hip_runtime.h>
#include <cstdint>
#include <cstddef>

typedef _Float16 h16;
typedef _Float16 h16x4 __attribute__((ext_vector_type(4)));
typedef _Float16 h16x8 __attribute__((ext_vector_type(8)));
typedef __fp16 fp16x2 __attribute__((ext_vector_type(2)));
typedef float f32x4 __attribute__((ext_vector_type(4)));

#define LOG2E 1.44269504088896f
#define QSCALE (0.125f * LOG2E)
#define THR 11.0f

static __device__ __forceinline__ f32x4 mfma_f16(h16x8 a, h16x8 b, f32x4 c) {
  return __builtin_amdgcn_mfma_f32_16x16x32_f16(a, b, c, 0, 0, 0);
}

static __device__ __forceinline__ void gload_lds16(const void* g, void* s) {
  __builtin_amdgcn_global_load_lds(
      (__attribute__((address_space(1))) void*)(uintptr_t)g,
      (__attribute__((address_space(3))) void*)s, 16, 0, 0);
}

// ---------------- fp32 -> fp16 convert (vectorized) ----------------
__global__ __launch_bounds__(256) void k_cvt(const float* __restrict__ in,
                                             h16* __restrict__ out, int n) {
  int i = (blockIdx.x * 256 + threadIdx.x) * 8;
  if (i >= n) return;
  float4 a = *(const float4*)(in + i);
  float4 b = *(const float4*)(in + i + 4);
  h16x8 o;
  o[0] = (h16)a.x; o[1] = (h16)a.y; o[2] = (h16)a.z; o[3] = (h16)a.w;
  o[4] = (h16)b.x; o[5] = (h16)b.y; o[6] = (h16)b.z; o[7] = (h16)b.w;
  *(h16x8*)(out + i) = o;
}

// ---------------- fp32 [R][C] -> fp16 [C][R] transpose-convert ----------------
__global__ __launch_bounds__(256) void k_tr_cvt(const float* __restrict__ in,
                                                h16* __restrict__ out, int R, int C) {
  __shared__ float tile[32][33];
  int c0 = blockIdx.x * 32, r0 = blockIdx.y * 32;
  int tx = threadIdx.x & 31, ty = threadIdx.x >> 5;
#pragma unroll
  for (int i = 0; i < 4; i++) {
    int r = ty + i * 8;
    tile[r][tx] = in[(size_t)(r0 + r) * C + c0 + tx];
  }
  __syncthreads();
#pragma unroll
  for (int i = 0; i < 4; i++) {
    int c = ty + i * 8;
    out[(size_t)(c0 + c) * R + r0 + tx] = (h16)tile[tx][c];
  }
}

// ---------------- 128x128 tile GEMM mainloop: C = A[M][K] * BT[N][K]^T ----------------
static __device__ __forceinline__ void gemm_main(const h16* __restrict__ A,
                                                 const h16* __restrict__ BT,
                                                 int K, int m0, int n0,
                                                 h16* sA, h16* sB, f32x4 acc[4][4]) {
  const int t = threadIdx.x;
  const int l = t & 63, w = t >> 6;
  const int lm = l & 15, lh = l >> 4;
  const int wm = (w >> 1) * 64, wn = (w & 1) * 64;

  const h16* gA0 = A + (size_t)(m0 + (t >> 2)) * K + (t & 3) * 8;
  const h16* gB0 = BT + (size_t)(n0 + (t >> 2)) * K + (t & 3) * 8;
  h16* sAw = sA + w * 512;
  h16* sBw = sB + w * 512;

  for (int k0 = 0; k0 < K; k0 += 32) {
    gload_lds16(gA0 + k0, sAw);
    gload_lds16(gA0 + (size_t)64 * K + k0, sAw + 2048);
    gload_lds16(gB0 + k0, sBw);
    gload_lds16(gB0 + (size_t)64 * K + k0, sBw + 2048);
    __syncthreads();
    h16x8 af[4], bfv[4];
#pragma unroll
    for (int mi = 0; mi < 4; mi++)
      af[mi] = *(const h16x8*)(sA + (wm + mi * 16 + lm) * 32 + lh * 8);
#pragma unroll
    for (int ni = 0; ni < 4; ni++)
      bfv[ni] = *(const h16x8*)(sB + (wn + ni * 16 + lm) * 32 + lh * 8);
#pragma unroll
    for (int mi = 0; mi < 4; mi++)
#pragma unroll
      for (int ni = 0; ni < 4; ni++)
        acc[mi][ni] = mfma_f16(af[mi], bfv[ni], acc[mi][ni]);
    __syncthreads();
  }
}

// ---------------- GEMM1: qkv = x @ W_attn + b; scatter q,k:[B,Nh,S,Ne], v^T:[B,Nh,Ne,S] ----------------
__global__ __launch_bounds__(256) void k_gemm_qkv(const h16* __restrict__ xb,
                                                  const h16* __restrict__ WTa,
                                                  const float* __restrict__ b_attn,
                                                  h16* __restrict__ qb, h16* __restrict__ kbuf,
                                                  h16* __restrict__ vT) {
  __shared__ __align__(16) h16 sA[128 * 32];
  __shared__ __align__(16) h16 sB[128 * 32];
  f32x4 acc[4][4];
#pragma unroll
  for (int i = 0; i < 4; i++)
#pragma unroll
    for (int j = 0; j < 4; j++) acc[i][j] = (f32x4){0.f, 0.f, 0.f, 0.f};
  const int n0 = blockIdx.x * 128, m0 = blockIdx.y * 128;
  gemm_main(xb, WTa, 1024, m0, n0, sA, sB, acc);

  const int t = threadIdx.x, l = t & 63, w = t >> 6;
  const int lm = l & 15, lh = l >> 4;
  const int wm = (w >> 1) * 64, wn = (w & 1) * 64;
#pragma unroll
  for (int mi = 0; mi < 4; mi++) {
#pragma unroll
    for (int ni = 0; ni < 4; ni++) {
      const int n = n0 + wn + ni * 16 + lm;
      const float bias = b_attn[n];
      const int which = n >> 10, c = n & 1023, h = c >> 6, e = c & 63;
#pragma unroll
      for (int r = 0; r < 4; r++) {
        const int m = m0 + wm + mi * 16 + lh * 4 + r;
        const int b = m >> 11, s = m & 2047;
        const h16 o = (h16)(acc[mi][ni][r] + bias);
        const size_t bh = (size_t)(b * 16 + h);
        if (which == 0)      qb[(bh * 2048 + s) * 64 + e] = o;
        else if (which == 1) kbuf[(bh * 2048 + s) * 64 + e] = o;
        else                 vT[(bh * 64 + e) * 2048 + s] = o;
      }
    }
  }
}

// ---------------- GEMM2: out = y @ W_proj + b (fp32 out) ----------------
__global__ __launch_bounds__(256) void k_gemm_proj(const h16* __restrict__ yb,
                                                   const h16* __restrict__ WTp,
                                                   const float* __restrict__ b_proj,
                                                   float* __restrict__ out) {
  __shared__ __align__(16) h16 sA[128 * 32];
  __shared__ __align__(16) h16 sB[128 * 32];
  f32x4 acc[4][4];
#pragma unroll
  for (int i = 0; i < 4; i++)
#pragma unroll
    for (int j = 0; j < 4; j++) acc[i][j] = (f32x4){0.f, 0.f, 0.f, 0.f};
  const int n0 = blockIdx.x * 128, m0 = blockIdx.y * 128;
  gemm_main(yb, WTp, 1024, m0, n0, sA, sB, acc);

  const int t = threadIdx.x, l = t & 63, w = t >> 6;
  const int lm = l & 15, lh = l >> 4;
  const int wm = (w >> 1) * 64, wn = (w & 1) * 64;
#pragma unroll
  for (int mi = 0; mi < 4; mi++) {
#pragma unroll
    for (int ni = 0; ni < 4; ni++) {
      const int n = n0 + wn + ni * 16 + lm;
      const float bias = b_proj[n];
#pragma unroll
      for (int r = 0; r < 4; r++) {
        const int m = m0 + wm + mi * 16 + lh * 4 + r;
        out[(size_t)m * 1024 + n] = acc[mi][ni][r] + bias;
      }
    }
  }
}

// ---------------- causal flash attention, v3.1 ----------------
// Swapped QK^T: lane(lm,lh) holds S[q=lm][kcol=ct*16+lh*4+r] -> each q-row is
// SPLIT across the 4 lanes sharing lm. Row max/sum therefore need a 4-lane
// group reduce (shfl_xor 16,32) -- that was the v3 bug.
__global__ __launch_bounds__(256, 3) void k_attn(const h16* __restrict__ qb,
                                                 const h16* __restrict__ kbuf,
                                                 const h16* __restrict__ vT,
                                                 h16* __restrict__ yb) {
  __shared__ __align__(16) h16 sKt[2][64 * 64];
  __shared__ __align__(16) h16 sVt[2][64 * 64];
  __shared__ __align__(16) h16 sP[4][2][16 * 64];

  const int bid = blockIdx.x;
  const int bh = bid & 63;          // same-head blocks 64 apart -> same XCD
  const int qt = 15 - (bid >> 6);   // long blocks dispatch first
  const int b = bh >> 4, h = bh & 15;
  const int tid = threadIdx.x, lam = tid & 63, w = tid >> 6;
  const int lm = lam & 15, lh = lam >> 4;
  const int q0 = qt * 128 + w * 32;
  const h16* Q = qb + (size_t)bh * 2048 * 64;
  const h16* Kp = kbuf + (size_t)bh * 2048 * 64;
  const h16* Vp = vT + (size_t)bh * 64 * 2048;

  // staging geometry: each wave stages K segs {2w,2w+1} + V segs {2w,2w+1}
  // (1 KB each). LDS linear; global source pre-swizzled so reads can XOR.
  const int srow = lam >> 3;                         // row within 8-row seg
  const int xo8 = (((lam & 7) ^ (srow & 7)) << 3);   // swizzled elem offset

  // Q fragments (B-operand: col=q=lm, k=d), prescaled into exp2 domain
  h16x8 qf[2][2];
#pragma unroll
  for (int rt = 0; rt < 2; rt++)
#pragma unroll
    for (int dc = 0; dc < 2; dc++) {
      h16x8 qv = *(const h16x8*)(Q + (size_t)(q0 + rt * 16 + lm) * 64 + dc * 32 + lh * 8);
      h16x8 o;
#pragma unroll
      for (int i = 0; i < 8; i++) o[i] = (h16)((float)qv[i] * QSCALE);
      qf[rt][dc] = o;
    }

  f32x4 yacc[2][4];
  float m2[2], lw[2];
#pragma unroll
  for (int rt = 0; rt < 2; rt++) {
    m2[rt] = -1e30f;
    lw[rt] = 0.f;
#pragma unroll
    for (int i = 0; i < 4; i++) yacc[rt][i] = (f32x4){0.f, 0.f, 0.f, 0.f};
  }

  const int nsteps = qt * 2 + 2;

  // prologue: stage tile 0 into buf 0
#pragma unroll
  for (int i = 0; i < 2; i++) {
    const int seg = 2 * w + i;
    const int r = seg * 8 + srow;
    gload_lds16(Kp + (size_t)r * 64 + xo8, &sKt[0][seg * 512]);
    gload_lds16(Vp + (size_t)r * 2048 + xo8, &sVt[0][seg * 512]);
  }
  asm volatile("s_waitcnt vmcnt(0)" ::: "memory");
  __syncthreads();

  for (int tt = 0; tt < nsteps; ++tt) {
    const int kb0 = tt * 64, cur = tt & 1;
    if (tt + 1 < nsteps) {  // stage next tile into buf cur^1 (issue early)
      const int kn = kb0 + 64;
#pragma unroll
      for (int i = 0; i < 2; i++) {
        const int seg = 2 * w + i;
        const int r = seg * 8 + srow;
        gload_lds16(Kp + (size_t)(kn + r) * 64 + xo8, &sKt[cur ^ 1][seg * 512]);
        gload_lds16(Vp + (size_t)r * 2048 + kn + xo8, &sVt[cur ^ 1][seg * 512]);
      }
    }
    if (kb0 <= q0 + 31) {  // wave-uniform: skip fully-masked tiles
      const bool domask = (kb0 + 63 > q0);
      // K fragments (A-operand: row=kcol=ct*16+lm, k=d)
      h16x8 kf[4][2];
#pragma unroll
      for (int ct = 0; ct < 4; ct++)
#pragma unroll
        for (int dc = 0; dc < 2; dc++)
          kf[ct][dc] = *(const h16x8*)(
              &sKt[cur][(ct * 16 + lm) * 64 + ((dc * 32 + lh * 8) ^ ((lm & 7) << 3))]);
      // V fragments (A-operand for PV: row=d=dt*16+lm, k=kcol)
      h16x8 vf[4][2];
#pragma unroll
      for (int dt = 0; dt < 4; dt++)
#pragma unroll
        for (int kc = 0; kc < 2; kc++)
          vf[dt][kc] = *(const h16x8*)(
              &sVt[cur][(dt * 16 + lm) * 64 + ((kc * 32 + lh * 8) ^ ((lm & 7) << 3))]);

#pragma unroll
      for (int rt = 0; rt < 2; rt++) {
        const int qrow = q0 + rt * 16 + lm;  // this lane's q-row
        f32x4 sv[4];
        __builtin_amdgcn_s_setprio(1);
#pragma unroll
        for (int ct = 0; ct < 4; ct++) {
          f32x4 s = mfma_f16(kf[ct][0], qf[rt][0], (f32x4){0.f, 0.f, 0.f, 0.f});
          sv[ct] = mfma_f16(kf[ct][1], qf[rt][1], s);
        }
        __builtin_amdgcn_s_setprio(0);
        if (domask) {
#pragma unroll
          for (int ct = 0; ct < 4; ct++)
#pragma unroll
            for (int r = 0; r < 4; r++)
              if (kb0 + ct * 16 + lh * 4 + r > qrow) sv[ct][r] = -1e30f;
        }
        // row max: lane-local 16 values, then 4-lane group reduce (lh axis)
        float rm = fmaxf(fmaxf(fmaxf(sv[0][0], sv[0][1]), fmaxf(sv[0][2], sv[0][3])),
                         fmaxf(fmaxf(sv[1][0], sv[1][1]), fmaxf(sv[1][2], sv[1][3])));
        rm = fmaxf(rm, fmaxf(fmaxf(fmaxf(sv[2][0], sv[2][1]), fmaxf(sv[2][2], sv[2][3])),
                             fmaxf(fmaxf(sv[3][0], sv[3][1]), fmaxf(sv[3][2], sv[3][3]))));
        rm = fmaxf(rm, __shfl_xor(rm, 16));
        rm = fmaxf(rm, __shfl_xor(rm, 32));
        // T13 defer-max: rescale only when some row's max grew past THR
        if (!__all(rm <= m2[rt] + THR)) {
          const float nm = fmaxf(m2[rt], rm);
          const float alpha = __builtin_amdgcn_exp2f(m2[rt] - nm);
          m2[rt] = nm;
          lw[rt] *= alpha;
#pragma unroll
          for (int dt = 0; dt < 4; dt++) yacc[rt][dt] *= alpha;
        }
        // p = exp2(s - m); lane-partial sum; packed b32 writes to swizzled P
        const float m = m2[rt];
        float psum = 0.f;
#pragma unroll
        for (int ct = 0; ct < 4; ct++) {
          const float p0 = __builtin_amdgcn_exp2f(sv[ct][0] - m);
          const float p1 = __builtin_amdgcn_exp2f(sv[ct][1] - m);
          const float p2 = __builtin_amdgcn_exp2f(sv[ct][2] - m);
          const float p3 = __builtin_amdgcn_exp2f(sv[ct][3] - m);
          psum += (p0 + p1) + (p2 + p3);
          const fp16x2 u0 = __builtin_amdgcn_cvt_pkrtz(p0, p1);
          const fp16x2 u1 = __builtin_amdgcn_cvt_pkrtz(p2, p3);
          const int base = ct * 16 + lh * 4;
          *(fp16x2*)(&sP[w][rt][lm * 64 + ((base + 0) ^ ((lm & 7) << 3))]) = u0;
          *(fp16x2*)(&sP[w][rt][lm * 64 + ((base + 2) ^ ((lm & 7) << 3))]) = u1;
        }
        lw[rt] += psum;
      }
      // PV: yacc[rt][dt] += V^T . P  (C: row=d, col=q=lm)
#pragma unroll
      for (int rt = 0; rt < 2; rt++) {
        const h16x8 pf0 = *(const h16x8*)(
            &sP[w][rt][lm * 64 + ((lh * 8) ^ ((lm & 7) << 3))]);
        const h16x8 pf1 = *(const h16x8*)(
            &sP[w][rt][lm * 64 + ((32 + lh * 8) ^ ((lm & 7) << 3))]);
        __builtin_amdgcn_s_setprio(1);
#pragma unroll
        for (int dt = 0; dt < 4; dt++) {
          f32x4 y = mfma_f16(vf[dt][0], pf0, yacc[rt][dt]);
          yacc[rt][dt] = mfma_f16(vf[dt][1], pf1, y);
        }
        __builtin_amdgcn_s_setprio(0);
      }
    }
    asm volatile("s_waitcnt vmcnt(0)" ::: "memory");
    __syncthreads();
  }

  // epilogue: group-reduce row sums (lh axis), normalize, 8B packed stores
#pragma unroll
  for (int rt = 0; rt < 2; rt++) {
    float s = lw[rt];
    s += __shfl_xor(s, 16);
    s += __shfl_xor(s, 32);
    const float inv = 1.0f / s;
    const int q = q0 + rt * 16 + lm;
    const size_t yrow = ((size_t)b * 2048 + q) * 1024 + h * 64;
#pragma unroll
    for (int dt = 0; dt < 4; dt++) {
      h16x4 o;
#pragma unroll
      for (int r = 0; r < 4; r++) o[r] = (h16)(yacc[rt][dt][r] * inv);
      *(h16x4*)(yb + yrow + dt * 16 + lh * 4) = o;
    }
  }
}

extern "C" void kernel_launch(void* const* d_in, const int* in_sizes, int n_in,
                              void* d_out, int out_size, void* d_ws, size_t ws_size,
                              hipStream_t stream) {
  const float* x      = (const float*)d_in[0];
  const float* W_attn = (const float*)d_in[1];
  const float* b_attn = (const float*)d_in[2];
  const float* W_proj = (const float*)d_in[3];
  const float* b_proj = (const float*)d_in[4];
  float* out = (float*)d_out;

  char* ws = (char*)d_ws;
  h16* xb   = (h16*)(ws);                 // 16 MB  [8192][1024] fp16 (reused as yb)
  h16* WTa  = (h16*)(ws + 16777216);      // 6 MB   [3072][1024]
  h16* WTp  = (h16*)(ws + 23068672);      // 2 MB   [1024][1024]
  h16* qb   = (h16*)(ws + 25165824);      // 16 MB  [B,Nh,S,Ne]
  h16* kbuf = (h16*)(ws + 41943040);      // 16 MB  [B,Nh,S,Ne]
  h16* vT   = (h16*)(ws + 58720256);      // 16 MB  [B,Nh,Ne,S]
  h16* yb   = xb;                         // reuse x buffer for attention output

  k_cvt<<<dim3(8192 * 1024 / 2048), 256, 0, stream>>>(x, xb, 8192 * 1024);
  k_tr_cvt<<<dim3(3072 / 32, 1024 / 32), 256, 0, stream>>>(W_attn, WTa, 1024, 3072);
  k_tr_cvt<<<dim3(1024 / 32, 1024 / 32), 256, 0, stream>>>(W_proj, WTp, 1024, 1024);
  k_gemm_qkv<<<dim3(3072 / 128, 8192 / 128), 256, 0, stream>>>(xb, WTa, b_attn, qb, kbuf, vT);
  k_attn<<<dim3(64 * 16), 256, 0, stream>>>(qb, kbuf, vT, yb);
  k_gemm_proj<<<dim3(1024 / 128, 8192 / 128), 256, 0, stream>>>(yb, WTp, b_proj, out);
}

// Round 6
// 290.901 us; speedup vs baseline: 2.2610x; 1.0295x over previous
//
#include <hip/hip_runtime.h>
#include <cstdint>
#include <cstddef>

typedef _Float16 h16;
typedef _Float16 h16x4 __attribute__((ext_vector_type(4)));
typedef _Float16 h16x8 __attribute__((ext_vector_type(8)));
typedef __fp16 fp16x2 __attribute__((ext_vector_type(2)));
typedef float f32x4 __attribute__((ext_vector_type(4)));

#define LOG2E 1.44269504088896f
#define QSCALE (0.125f * LOG2E)
#define THR 11.0f

static __device__ __forceinline__ f32x4 mfma_f16(h16x8 a, h16x8 b, f32x4 c) {
  return __builtin_amdgcn_mfma_f32_16x16x32_f16(a, b, c, 0, 0, 0);
}

static __device__ __forceinline__ void gload_lds16(const void* g, void* s) {
  __builtin_amdgcn_global_load_lds(
      (__attribute__((address_space(1))) void*)(uintptr_t)g,
      (__attribute__((address_space(3))) void*)s, 16, 0, 0);
}

// ---------------- fp32 -> fp16 convert (vectorized) ----------------
__global__ __launch_bounds__(256) void k_cvt(const float* __restrict__ in,
                                             h16* __restrict__ out, int n) {
  int i = (blockIdx.x * 256 + threadIdx.x) * 8;
  if (i >= n) return;
  float4 a = *(const float4*)(in + i);
  float4 b = *(const float4*)(in + i + 4);
  h16x8 o;
  o[0] = (h16)a.x; o[1] = (h16)a.y; o[2] = (h16)a.z; o[3] = (h16)a.w;
  o[4] = (h16)b.x; o[5] = (h16)b.y; o[6] = (h16)b.z; o[7] = (h16)b.w;
  *(h16x8*)(out + i) = o;
}

// ---------------- fp32 [R][C] -> fp16 [C][R] transpose-convert ----------------
__global__ __launch_bounds__(256) void k_tr_cvt(const float* __restrict__ in,
                                                h16* __restrict__ out, int R, int C) {
  __shared__ float tile[32][33];
  int c0 = blockIdx.x * 32, r0 = blockIdx.y * 32;
  int tx = threadIdx.x & 31, ty = threadIdx.x >> 5;
#pragma unroll
  for (int i = 0; i < 4; i++) {
    int r = ty + i * 8;
    tile[r][tx] = in[(size_t)(r0 + r) * C + c0 + tx];
  }
  __syncthreads();
#pragma unroll
  for (int i = 0; i < 4; i++) {
    int c = ty + i * 8;
    out[(size_t)(c0 + c) * R + r0 + tx] = (h16)tile[tx][c];
  }
}

// ============ 256x128 tile GEMM, BK=64, triple-buffered counted-vmcnt ============
// 512 threads = 8 waves (4M x 2N), per-wave 64x64 output. K fixed = 1024.
// LDS per slot: A 256x64 (16384 h16) + B 128x64 (8192 h16) = 24576 h16; 3 slots.
// XOR-swizzle: 16B slot within 128B row ^= (row&7); staged via pre-swizzled
// global source (linear LDS dest as global_load_lds requires).
#define SLOT_H16 24576
#define NT_K 16

static __device__ __forceinline__ void gemm_main256(
    const h16* __restrict__ A, const h16* __restrict__ BT,
    int m0, int n0, h16* sAB, f32x4 acc[4][4]) {
  const int tid = threadIdx.x;
  const int lane = tid & 63, w = tid >> 6;
  const int lm = lane & 15, lh = lane >> 4;
  const int wr = w >> 1, wc = w & 1;
  const int wbase = w * 512;       // wave-uniform LDS chunk offset (h16)
  const int srow = tid >> 3;       // row within 64-row chunk
  const int scol = (((tid & 7) ^ (srow & 7)) << 3);  // pre-swizzled src col
  const h16* gA = A + (size_t)(m0 + srow) * 1024 + scol;
  const h16* gB = BT + (size_t)(n0 + srow) * 1024 + scol;

  auto stage = [&](int t, int sl) {
    const int k = t * 64;
    h16* d = sAB + sl * SLOT_H16 + wbase;
    gload_lds16(gA + (size_t)0 * 65536 + k, d + 0 * 4096);
    gload_lds16(gA + (size_t)1 * 65536 + k, d + 1 * 4096);
    gload_lds16(gA + (size_t)2 * 65536 + k, d + 2 * 4096);
    gload_lds16(gA + (size_t)3 * 65536 + k, d + 3 * 4096);
    gload_lds16(gB + (size_t)0 * 65536 + k, d + 16384 + 0 * 4096);
    gload_lds16(gB + (size_t)1 * 65536 + k, d + 16384 + 1 * 4096);
  };

  // prologue: stage T0->slot0, T1->slot1; wait T0 (6 of 12 outstanding)
  stage(0, 0);
  stage(1, 1);
  asm volatile("s_waitcnt vmcnt(6)" ::: "memory");
  __builtin_amdgcn_s_barrier();

  int sl = 0, ss = 2;  // compute slot, stage slot (t+2)%3
  for (int t = 0; t < NT_K; ++t) {
    if (t < NT_K - 2) stage(t + 2, ss);   // issue early; prev barrier made ss safe
    const h16* sa = sAB + sl * SLOT_H16;
    const h16* sb = sa + 16384;
    h16x8 af[4][2], bf[4][2];
#pragma unroll
    for (int mi = 0; mi < 4; mi++) {
      const int row = wr * 64 + mi * 16 + lm;
#pragma unroll
      for (int kk = 0; kk < 2; kk++)
        af[mi][kk] = *(const h16x8*)(sa + row * 64 + ((kk * 32 + lh * 8) ^ ((lm & 7) << 3)));
    }
#pragma unroll
    for (int ni = 0; ni < 4; ni++) {
      const int row = wc * 64 + ni * 16 + lm;
#pragma unroll
      for (int kk = 0; kk < 2; kk++)
        bf[ni][kk] = *(const h16x8*)(sb + row * 64 + ((kk * 32 + lh * 8) ^ ((lm & 7) << 3)));
    }
    __builtin_amdgcn_s_setprio(1);
#pragma unroll
    for (int mi = 0; mi < 4; mi++)
#pragma unroll
      for (int ni = 0; ni < 4; ni++)
        acc[mi][ni] = mfma_f16(af[mi][1], bf[ni][1],
                               mfma_f16(af[mi][0], bf[ni][0], acc[mi][ni]));
    __builtin_amdgcn_s_setprio(0);
    // counted wait: T(t+1) landed; only T(t+2)'s 6 loads may remain in flight
    if (t < NT_K - 2) asm volatile("s_waitcnt vmcnt(6)" ::: "memory");
    else              asm volatile("s_waitcnt vmcnt(0)" ::: "memory");
    __builtin_amdgcn_s_barrier();
    sl = (sl == 2) ? 0 : sl + 1;
    ss = (ss == 2) ? 0 : ss + 1;
  }
}

// ---------------- GEMM1: qkv = x @ W_attn + b; scatter q,k:[B,Nh,S,Ne], v^T:[B,Nh,Ne,S] ----------------
__global__ __launch_bounds__(512, 2) void k_gemm_qkv(const h16* __restrict__ xb,
                                                     const h16* __restrict__ WTa,
                                                     const float* __restrict__ b_attn,
                                                     h16* __restrict__ qb,
                                                     h16* __restrict__ kbuf,
                                                     h16* __restrict__ vT) {
  __shared__ __align__(16) h16 sAB[3 * SLOT_H16];
  const int bid = blockIdx.x;
  const int flat = (bid & 7) * 96 + (bid >> 3);  // bijective XCD swizzle (768%8==0)
  const int mt = flat / 24, nt = flat % 24;      // M-panel-major: neighbors share A
  const int m0 = mt * 256, n0 = nt * 128;
  f32x4 acc[4][4];
#pragma unroll
  for (int i = 0; i < 4; i++)
#pragma unroll
    for (int j = 0; j < 4; j++) acc[i][j] = (f32x4){0.f, 0.f, 0.f, 0.f};
  gemm_main256(xb, WTa, m0, n0, sAB, acc);

  const int tid = threadIdx.x, lane = tid & 63, w = tid >> 6;
  const int lm = lane & 15, lh = lane >> 4;
  const int wr = w >> 1, wc = w & 1;
#pragma unroll
  for (int ni = 0; ni < 4; ni++) {
    const int n = n0 + wc * 64 + ni * 16 + lm;
    const float bias = b_attn[n];
    const int which = n >> 10, cc = n & 1023, hh = cc >> 6, e = cc & 63;
#pragma unroll
    for (int mi = 0; mi < 4; mi++) {
#pragma unroll
      for (int r = 0; r < 4; r++) {
        const int m = m0 + wr * 64 + mi * 16 + lh * 4 + r;
        const int b = m >> 11, s = m & 2047;
        const h16 o = (h16)(acc[mi][ni][r] + bias);
        const size_t bh = (size_t)(b * 16 + hh);
        if (which == 0)      qb[(bh * 2048 + s) * 64 + e] = o;
        else if (which == 1) kbuf[(bh * 2048 + s) * 64 + e] = o;
        else                 vT[(bh * 64 + e) * 2048 + s] = o;
      }
    }
  }
}

// ---------------- GEMM2: out = y @ W_proj + b (fp32 out) ----------------
__global__ __launch_bounds__(512, 2) void k_gemm_proj(const h16* __restrict__ yb,
                                                      const h16* __restrict__ WTp,
                                                      const float* __restrict__ b_proj,
                                                      float* __restrict__ out) {
  __shared__ __align__(16) h16 sAB[3 * SLOT_H16];
  const int bid = blockIdx.x;
  const int flat = (bid & 7) * 32 + (bid >> 3);  // 256%8==0
  const int mt = flat / 8, nt = flat % 8;
  const int m0 = mt * 256, n0 = nt * 128;
  f32x4 acc[4][4];
#pragma unroll
  for (int i = 0; i < 4; i++)
#pragma unroll
    for (int j = 0; j < 4; j++) acc[i][j] = (f32x4){0.f, 0.f, 0.f, 0.f};
  gemm_main256(yb, WTp, m0, n0, sAB, acc);

  const int tid = threadIdx.x, lane = tid & 63, w = tid >> 6;
  const int lm = lane & 15, lh = lane >> 4;
  const int wr = w >> 1, wc = w & 1;
#pragma unroll
  for (int ni = 0; ni < 4; ni++) {
    const int n = n0 + wc * 64 + ni * 16 + lm;
    const float bias = b_proj[n];
#pragma unroll
    for (int mi = 0; mi < 4; mi++) {
#pragma unroll
      for (int r = 0; r < 4; r++) {
        const int m = m0 + wr * 64 + mi * 16 + lh * 4 + r;
        out[(size_t)m * 1024 + n] = acc[mi][ni][r] + bias;
      }
    }
  }
}

// ---------------- causal flash attention (R5, unchanged) ----------------
__global__ __launch_bounds__(256, 3) void k_attn(const h16* __restrict__ qb,
                                                 const h16* __restrict__ kbuf,
                                                 const h16* __restrict__ vT,
                                                 h16* __restrict__ yb) {
  __shared__ __align__(16) h16 sKt[2][64 * 64];
  __shared__ __align__(16) h16 sVt[2][64 * 64];
  __shared__ __align__(16) h16 sP[4][2][16 * 64];

  const int bid = blockIdx.x;
  const int bh = bid & 63;          // same-head blocks 64 apart -> same XCD
  const int qt = 15 - (bid >> 6);   // long blocks dispatch first
  const int b = bh >> 4, h = bh & 15;
  const int tid = threadIdx.x, lam = tid & 63, w = tid >> 6;
  const int lm = lam & 15, lh = lam >> 4;
  const int q0 = qt * 128 + w * 32;
  const h16* Q = qb + (size_t)bh * 2048 * 64;
  const h16* Kp = kbuf + (size_t)bh * 2048 * 64;
  const h16* Vp = vT + (size_t)bh * 64 * 2048;

  const int srow = lam >> 3;
  const int xo8 = (((lam & 7) ^ (srow & 7)) << 3);

  h16x8 qf[2][2];
#pragma unroll
  for (int rt = 0; rt < 2; rt++)
#pragma unroll
    for (int dc = 0; dc < 2; dc++) {
      h16x8 qv = *(const h16x8*)(Q + (size_t)(q0 + rt * 16 + lm) * 64 + dc * 32 + lh * 8);
      h16x8 o;
#pragma unroll
      for (int i = 0; i < 8; i++) o[i] = (h16)((float)qv[i] * QSCALE);
      qf[rt][dc] = o;
    }

  f32x4 yacc[2][4];
  float m2[2], lw[2];
#pragma unroll
  for (int rt = 0; rt < 2; rt++) {
    m2[rt] = -1e30f;
    lw[rt] = 0.f;
#pragma unroll
    for (int i = 0; i < 4; i++) yacc[rt][i] = (f32x4){0.f, 0.f, 0.f, 0.f};
  }

  const int nsteps = qt * 2 + 2;

#pragma unroll
  for (int i = 0; i < 2; i++) {
    const int seg = 2 * w + i;
    const int r = seg * 8 + srow;
    gload_lds16(Kp + (size_t)r * 64 + xo8, &sKt[0][seg * 512]);
    gload_lds16(Vp + (size_t)r * 2048 + xo8, &sVt[0][seg * 512]);
  }
  asm volatile("s_waitcnt vmcnt(0)" ::: "memory");
  __syncthreads();

  for (int tt = 0; tt < nsteps; ++tt) {
    const int kb0 = tt * 64, cur = tt & 1;
    if (tt + 1 < nsteps) {
      const int kn = kb0 + 64;
#pragma unroll
      for (int i = 0; i < 2; i++) {
        const int seg = 2 * w + i;
        const int r = seg * 8 + srow;
        gload_lds16(Kp + (size_t)(kn + r) * 64 + xo8, &sKt[cur ^ 1][seg * 512]);
        gload_lds16(Vp + (size_t)r * 2048 + kn + xo8, &sVt[cur ^ 1][seg * 512]);
      }
    }
    if (kb0 <= q0 + 31) {
      const bool domask = (kb0 + 63 > q0);
      h16x8 kf[4][2];
#pragma unroll
      for (int ct = 0; ct < 4; ct++)
#pragma unroll
        for (int dc = 0; dc < 2; dc++)
          kf[ct][dc] = *(const h16x8*)(
              &sKt[cur][(ct * 16 + lm) * 64 + ((dc * 32 + lh * 8) ^ ((lm & 7) << 3))]);
      h16x8 vf[4][2];
#pragma unroll
      for (int dt = 0; dt < 4; dt++)
#pragma unroll
        for (int kc = 0; kc < 2; kc++)
          vf[dt][kc] = *(const h16x8*)(
              &sVt[cur][(dt * 16 + lm) * 64 + ((kc * 32 + lh * 8) ^ ((lm & 7) << 3))]);

#pragma unroll
      for (int rt = 0; rt < 2; rt++) {
        const int qrow = q0 + rt * 16 + lm;
        f32x4 sv[4];
        __builtin_amdgcn_s_setprio(1);
#pragma unroll
        for (int ct = 0; ct < 4; ct++) {
          f32x4 s = mfma_f16(kf[ct][0], qf[rt][0], (f32x4){0.f, 0.f, 0.f, 0.f});
          sv[ct] = mfma_f16(kf[ct][1], qf[rt][1], s);
        }
        __builtin_amdgcn_s_setprio(0);
        if (domask) {
#pragma unroll
          for (int ct = 0; ct < 4; ct++)
#pragma unroll
            for (int r = 0; r < 4; r++)
              if (kb0 + ct * 16 + lh * 4 + r > qrow) sv[ct][r] = -1e30f;
        }
        float rm = fmaxf(fmaxf(fmaxf(sv[0][0], sv[0][1]), fmaxf(sv[0][2], sv[0][3])),
                         fmaxf(fmaxf(sv[1][0], sv[1][1]), fmaxf(sv[1][2], sv[1][3])));
        rm = fmaxf(rm, fmaxf(fmaxf(fmaxf(sv[2][0], sv[2][1]), fmaxf(sv[2][2], sv[2][3])),
                             fmaxf(fmaxf(sv[3][0], sv[3][1]), fmaxf(sv[3][2], sv[3][3]))));
        rm = fmaxf(rm, __shfl_xor(rm, 16));
        rm = fmaxf(rm, __shfl_xor(rm, 32));
        if (!__all(rm <= m2[rt] + THR)) {
          const float nm = fmaxf(m2[rt], rm);
          const float alpha = __builtin_amdgcn_exp2f(m2[rt] - nm);
          m2[rt] = nm;
          lw[rt] *= alpha;
#pragma unroll
          for (int dt = 0; dt < 4; dt++) yacc[rt][dt] *= alpha;
        }
        const float m = m2[rt];
        float psum = 0.f;
#pragma unroll
        for (int ct = 0; ct < 4; ct++) {
          const float p0 = __builtin_amdgcn_exp2f(sv[ct][0] - m);
          const float p1 = __builtin_amdgcn_exp2f(sv[ct][1] - m);
          const float p2 = __builtin_amdgcn_exp2f(sv[ct][2] - m);
          const float p3 = __builtin_amdgcn_exp2f(sv[ct][3] - m);
          psum += (p0 + p1) + (p2 + p3);
          const fp16x2 u0 = __builtin_amdgcn_cvt_pkrtz(p0, p1);
          const fp16x2 u1 = __builtin_amdgcn_cvt_pkrtz(p2, p3);
          const int base = ct * 16 + lh * 4;
          *(fp16x2*)(&sP[w][rt][lm * 64 + ((base + 0) ^ ((lm & 7) << 3))]) = u0;
          *(fp16x2*)(&sP[w][rt][lm * 64 + ((base + 2) ^ ((lm & 7) << 3))]) = u1;
        }
        lw[rt] += psum;
      }
#pragma unroll
      for (int rt = 0; rt < 2; rt++) {
        const h16x8 pf0 = *(const h16x8*)(
            &sP[w][rt][lm * 64 + ((lh * 8) ^ ((lm & 7) << 3))]);
        const h16x8 pf1 = *(const h16x8*)(
            &sP[w][rt][lm * 64 + ((32 + lh * 8) ^ ((lm & 7) << 3))]);
        __builtin_amdgcn_s_setprio(1);
#pragma unroll
        for (int dt = 0; dt < 4; dt++) {
          f32x4 y = mfma_f16(vf[dt][0], pf0, yacc[rt][dt]);
          yacc[rt][dt] = mfma_f16(vf[dt][1], pf1, y);
        }
        __builtin_amdgcn_s_setprio(0);
      }
    }
    asm volatile("s_waitcnt vmcnt(0)" ::: "memory");
    __syncthreads();
  }

#pragma unroll
  for (int rt = 0; rt < 2; rt++) {
    float s = lw[rt];
    s += __shfl_xor(s, 16);
    s += __shfl_xor(s, 32);
    const float inv = 1.0f / s;
    const int q = q0 + rt * 16 + lm;
    const size_t yrow = ((size_t)b * 2048 + q) * 1024 + h * 64;
#pragma unroll
    for (int dt = 0; dt < 4; dt++) {
      h16x4 o;
#pragma unroll
      for (int r = 0; r < 4; r++) o[r] = (h16)(yacc[rt][dt][r] * inv);
      *(h16x4*)(yb + yrow + dt * 16 + lh * 4) = o;
    }
  }
}

extern "C" void kernel_launch(void* const* d_in, const int* in_sizes, int n_in,
                              void* d_out, int out_size, void* d_ws, size_t ws_size,
                              hipStream_t stream) {
  const float* x      = (const float*)d_in[0];
  const float* W_attn = (const float*)d_in[1];
  const float* b_attn = (const float*)d_in[2];
  const float* W_proj = (const float*)d_in[3];
  const float* b_proj = (const float*)d_in[4];
  float* out = (float*)d_out;

  char* ws = (char*)d_ws;
  h16* xb   = (h16*)(ws);                 // 16 MB  [8192][1024] fp16 (reused as yb)
  h16* WTa  = (h16*)(ws + 16777216);      // 6 MB   [3072][1024]
  h16* WTp  = (h16*)(ws + 23068672);      // 2 MB   [1024][1024]
  h16* qb   = (h16*)(ws + 25165824);      // 16 MB  [B,Nh,S,Ne]
  h16* kbuf = (h16*)(ws + 41943040);      // 16 MB  [B,Nh,S,Ne]
  h16* vT   = (h16*)(ws + 58720256);      // 16 MB  [B,Nh,Ne,S]
  h16* yb   = xb;                         // reuse x buffer for attention output

  k_cvt<<<dim3(8192 * 1024 / 2048), 256, 0, stream>>>(x, xb, 8192 * 1024);
  k_tr_cvt<<<dim3(3072 / 32, 1024 / 32), 256, 0, stream>>>(W_attn, WTa, 1024, 3072);
  k_tr_cvt<<<dim3(1024 / 32, 1024 / 32), 256, 0, stream>>>(W_proj, WTp, 1024, 1024);
  k_gemm_qkv<<<dim3(768), 512, 0, stream>>>(xb, WTa, b_attn, qb, kbuf, vT);
  k_attn<<<dim3(64 * 16), 256, 0, stream>>>(qb, kbuf, vT, yb);
  k_gemm_proj<<<dim3(256), 512, 0, stream>>>(yb, WTp, b_proj, out);
}